// Round 2
// baseline (12924.443 us; speedup 1.0000x reference)
//
#include <hip/hip_runtime.h>
#include <stdint.h>

typedef unsigned long long u64;
typedef unsigned int u32;

static constexpr u64 KEMPTY = ~0ull;
static constexpr int PROBE_CAP = 32768;

static __device__ __forceinline__ u64 mix64(u64 x){
  x ^= x >> 30; x *= 0xbf58476d1ce4e5b9ull;
  x ^= x >> 27; x *= 0x94d049bb133111ebull;
  x ^= x >> 31; return x;
}

static __device__ __forceinline__ long long lookup_slot(const u64* __restrict__ tk, u32 cmask, u64 code){
  u32 h = (u32)mix64(code) & cmask;
#pragma unroll 1
  for(int p=0;p<PROBE_CAP;p++){
    u64 cur = tk[h];
    if(cur==code) return (long long)h;
    if(cur==KEMPTY) return -1;
    h=(h+1)&cmask;
  }
  return -1;
}

static __device__ __forceinline__ void atomAddF(float* p, float v){
#if defined(__gfx90a__) || defined(__gfx940__) || defined(__gfx941__) || defined(__gfx942__) || defined(__gfx950__)
  unsafeAtomicAdd(p, v);
#else
  atomicAdd(p, v);
#endif
}

static __device__ __forceinline__ void row_load(const float* __restrict__ p, float* o){
  const float4* q=(const float4*)p;
#pragma unroll
  for(int i=0;i<4;i++){ float4 v=q[i]; o[4*i]=v.x; o[4*i+1]=v.y; o[4*i+2]=v.z; o[4*i+3]=v.w; }
}
static __device__ __forceinline__ void row_store(float* __restrict__ p, const float* o){
  float4* q=(float4*)p;
#pragma unroll
  for(int i=0;i<4;i++) q[i]=make_float4(o[4*i],o[4*i+1],o[4*i+2],o[4*i+3]);
}

// ---------------- kernel 1: elevate/rank/bary + table insert; stores SLOT in inv ----------------
__global__ void __launch_bounds__(256)
k_setup(const float* __restrict__ feat, int N,
        u64* __restrict__ tabk, u32 cmask,
        u32* __restrict__ inv_slot, float* __restrict__ bary)
{
#pragma clang fp contract(off)
  int n = blockIdx.x*256 + threadIdx.x;
  if(n>=N) return;

  // scale = (sqrt(2/3)*6) / sqrt((i+1)*(i+2)), rounded to f32 (matches jnp.asarray(..., f32))
  const float s0=3.4641016151377544f, s1=2.0f, s2=1.4142135623730951f,
              s3=1.0954451150103321f, s4=0.8944271909999159f;
  float c[5];
  c[0]=feat[n*5+0]*s0; c[1]=feat[n*5+1]*s1; c[2]=feat[n*5+2]*s2;
  c[3]=feat[n*5+3]*s3; c[4]=feat[n*5+4]*s4;

  float sfx[6]; sfx[5]=0.f;
#pragma unroll
  for(int i=4;i>=0;i--) sfx[i]=sfx[i+1]+c[i];     // same add order as jnp.cumsum of reversed
  float el[6];
  el[0]=sfx[0];
#pragma unroll
  for(int i=1;i<6;i++) el[i]=sfx[i]-(float)i*c[i-1];

  const float down=1.0f/6.0f;
  float rd[6], rem0[6], rdsum=0.f;
#pragma unroll
  for(int i=0;i<6;i++){ rd[i]=rintf(el[i]*down); rem0[i]=rd[i]*6.0f; rdsum+=rd[i]; }
  int sumi=(int)rdsum;

  float diff[6];
#pragma unroll
  for(int i=0;i<6;i++) diff[i]=(el[i]-rem0[i])*down;

  // stable descending rank
  int rank[6];
#pragma unroll
  for(int i=0;i<6;i++){
    int r=0;
#pragma unroll
    for(int j=0;j<6;j++)
      r += (diff[j]>diff[i]) || (diff[j]==diff[i] && j<i);
    rank[i]=r+sumi;
  }
  int rem0i[6];
#pragma unroll
  for(int i=0;i<6;i++){
    rem0i[i]=(int)rem0[i];
    int sh=(rank[i]<0)-(rank[i]>5);
    rank[i]+=6*sh; rem0i[i]+=6*sh;
  }

  // barycentric
  float b[7]={0.f,0.f,0.f,0.f,0.f,0.f,0.f};
#pragma unroll
  for(int i=0;i<6;i++){
    float t=(el[i]-(float)rem0i[i])*down;
    int k0=5-rank[i]; if(k0>=0&&k0<7) b[k0]+=t;
  }
#pragma unroll
  for(int i=0;i<6;i++){
    float t=(el[i]-(float)rem0i[i])*down;
    int k1=6-rank[i]; if(k1>=0&&k1<7) b[k1]-=t;
  }
  bary[(size_t)n*6+0]=(b[0]+1.0f)+b[6];
#pragma unroll
  for(int r=1;r<6;r++) bary[(size_t)n*6+r]=b[r];

  // 6 simplex-vertex codes -> insert -> remember slot
#pragma unroll 1
  for(int r=0;r<6;r++){
    long long code=0;
#pragma unroll
    for(int i=0;i<5;i++){
      int key = rem0i[i] + ((rank[i] >= 6-r) ? (r-6) : r);
      code = code*2048 + (long long)(key+1024);
    }
    u32 h=(u32)mix64((u64)code)&cmask;
    u32 slot=0xFFFFFFFFu;
#pragma unroll 1
    for(int p=0;p<PROBE_CAP;p++){
      u64 cur=tabk[h];
      if(cur==(u64)code){ slot=h; break; }
      if(cur==KEMPTY){
        u64 old=atomicCAS((unsigned long long*)&tabk[h], KEMPTY, (u64)code);
        if(old==KEMPTY || old==(u64)code){ slot=h; break; }
        // lost race to a different code: re-read this slot, then advance
      } else {
        h=(h+1)&cmask;
      }
    }
    inv_slot[(size_t)n*6+r]=slot;
  }
}

// ---------------- kernel 2: compact uids ----------------
__global__ void __launch_bounds__(256)
k_uid(const u64* __restrict__ tabk, u32 C, u32 Ucap, u32* __restrict__ tuid,
      u32* __restrict__ uidslot, u32* __restrict__ counter)
{
  u32 s=blockIdx.x*256+threadIdx.x;
  if(s>=C) return;
  if(tabk[s]==KEMPTY) return;
  u32 uid=atomicAdd(counter,1u);
  if(uid<Ucap) uidslot[uid]=s; else uid=0;  // overflow guard (should not happen)
  tuid[s]=uid;
}

// ---------------- kernel 3: slot -> uid in place ----------------
__global__ void __launch_bounds__(256)
k_inv(u32* __restrict__ inv, const u32* __restrict__ tuid, size_t M)
{
  size_t i=(size_t)blockIdx.x*256+threadIdx.x;
  if(i>=M) return;
  inv[i]=tuid[inv[i]];
}

// ---------------- kernel 4: splat ----------------
__global__ void __launch_bounds__(256)
k_splat(const float* __restrict__ values, int N,
        const u32* __restrict__ inv, const float* __restrict__ bary,
        float* __restrict__ val0)
{
  int n=blockIdx.x*256+threadIdx.x;
  if(n>=N) return;
  float v[16];
  row_load(values+(size_t)n*16, v);
#pragma unroll 1
  for(int r=0;r<6;r++){
    u32 u=inv[(size_t)n*6+r];
    float w=bary[(size_t)n*6+r];
    float* row=val0+(size_t)u*16;
#pragma unroll
    for(int k=0;k<16;k++) atomAddF(row+k, w*v[k]);
  }
}

// ---------------- kernel 5: one blur pass ----------------
__global__ void __launch_bounds__(256)
k_blur(const u64* __restrict__ tabk, const u32* __restrict__ tuid, u32 cmask,
       const u32* __restrict__ uidslot, const u32* __restrict__ counter, u32 Ucap,
       long long delta, const float* __restrict__ vin, float* __restrict__ vout)
{
  u32 m=blockIdx.x*256+threadIdx.x;
  u32 U=*counter; if(U>Ucap) U=Ucap;
  if(m>=U) return;
  long long code=(long long)tabk[uidslot[m]];
  long long sp=lookup_slot(tabk,cmask,(u64)(code+delta));
  long long sm=lookup_slot(tabk,cmask,(u64)(code-delta));
  float acc[16];
  row_load(vin+(size_t)m*16, acc);
#pragma unroll
  for(int k=0;k<16;k++) acc[k]*=0.5f;
  if(sp>=0){
    u32 u=tuid[sp]; float t[16]; row_load(vin+(size_t)u*16,t);
#pragma unroll
    for(int k=0;k<16;k++) acc[k]+=0.25f*t[k];
  }
  if(sm>=0){
    u32 u=tuid[sm]; float t[16]; row_load(vin+(size_t)u*16,t);
#pragma unroll
    for(int k=0;k<16;k++) acc[k]+=0.25f*t[k];
  }
  row_store(vout+(size_t)m*16, acc);
}

// ---------------- kernel 6: slice ----------------
__global__ void __launch_bounds__(256)
k_slice(const u32* __restrict__ inv, const float* __restrict__ bary,
        const float* __restrict__ val, int N, float* __restrict__ out)
{
  int n=blockIdx.x*256+threadIdx.x;
  if(n>=N) return;
  float acc[16];
#pragma unroll
  for(int k=0;k<16;k++) acc[k]=0.f;
#pragma unroll 1
  for(int r=0;r<6;r++){
    u32 u=inv[(size_t)n*6+r];
    float w=bary[(size_t)n*6+r];
    float t[16]; row_load(val+(size_t)u*16,t);
#pragma unroll
    for(int k=0;k<16;k++) acc[k]+=w*t[k];
  }
  const float alpha=0.9696969696969697f;  // 1/(1+2^-5)
  float4* q=(float4*)(out+(size_t)n*16);
#pragma unroll
  for(int i=0;i<4;i++) q[i]=make_float4(alpha*acc[4*i],alpha*acc[4*i+1],alpha*acc[4*i+2],alpha*acc[4*i+3]);
}

__global__ void k_diag(float* out, float v){ out[0]=v; }

// ---------------- host ----------------
extern "C" void kernel_launch(void* const* d_in, const int* in_sizes, int n_in,
                              void* d_out, int out_size, void* d_ws, size_t ws_size,
                              hipStream_t stream)
{
  const float* feat   =(const float*)d_in[0];
  const float* values =(const float*)d_in[1];
  float* out=(float*)d_out;
  int N=in_sizes[0]/5;
  size_t M=(size_t)N*6;

  // layout: counter, inv[M] u32, bary[M] f32, tabk[C] u64, tuid[C] u32,
  //         uidslot[U] u32, val0[U*16] f32, val1[U*16] f32
  auto need=[&](int lC,int lU)->size_t{
    size_t C=1ull<<lC, U=1ull<<lU, s=0;
    auto al=[&](size_t b){ s=(s+255)&~(size_t)255; s+=b; };
    al(4); al(M*4); al(M*4); al(C*8); al(C*4); al(U*4); al(U*64); al(U*64);
    return s+256;
  };
  // prefer bigger hash/capacity; all fp32 vals
  const int prefs[5][2]={{23,21},{22,20},{21,20},{21,19},{20,18}};
  int lC=0,lU=0;
  for(int i=0;i<5;i++){ if(need(prefs[i][0],prefs[i][1])<=ws_size){ lC=prefs[i][0]; lU=prefs[i][1]; break; } }
  if(!lC){
    hipMemsetAsync(d_out,0,(size_t)out_size*sizeof(float),stream);
    k_diag<<<1,1,0,stream>>>(out,(float)(ws_size>>20));
    return;
  }

  size_t C=1ull<<lC, Ucap=1ull<<lU; u32 cmask=(u32)(C-1);
  char* base=(char*)d_ws; size_t off=0;
  auto carve=[&](size_t b)->char*{ off=(off+255)&~(size_t)255; char* p=base+off; off+=b; return p; };
  u32*   counter=(u32*)carve(4);
  u32*   inv    =(u32*)carve(M*4);
  float* bary   =(float*)carve(M*4);
  u64*   tabk   =(u64*)carve(C*8);
  u32*   tuid   =(u32*)carve(C*4);
  u32*   uidslot=(u32*)carve(Ucap*4);
  float* v0     =(float*)carve(Ucap*64);
  float* v1     =(float*)carve(Ucap*64);

  hipMemsetAsync(counter,0,4,stream);
  hipMemsetAsync(tabk,0xFF,C*8,stream);   // KEMPTY
  hipMemsetAsync(v0,0,Ucap*64,stream);

  const int B=256;
  k_setup<<<(N+B-1)/B,B,0,stream>>>(feat,N,tabk,cmask,inv,bary);
  k_uid  <<<(u32)((C+B-1)/B),B,0,stream>>>(tabk,(u32)C,(u32)Ucap,tuid,uidslot,counter);
  k_inv  <<<(u32)((M+B-1)/B),B,0,stream>>>(inv,tuid,M);
  k_splat<<<(N+B-1)/B,B,0,stream>>>(values,N,inv,bary,v0);

  // blur deltas on packed code: weight of coord i is 2048^(4-i)
  const long long P[5]={1ll,2048ll,1ll<<22,1ll<<33,1ll<<44};
  const long long SUM=P[0]+P[1]+P[2]+P[3]+P[4];
  u32 gb=(u32)((Ucap+B-1)/B);
  float* a=v0; float* b=v1;
  for(int j=0;j<6;j++){
    long long delta=(j<5)? (SUM-6*P[4-j]) : SUM;
    k_blur<<<gb,B,0,stream>>>(tabk,tuid,cmask,uidslot,counter,(u32)Ucap,delta,a,b);
    float* t=a; a=b; b=t;
  }
  k_slice<<<(N+B-1)/B,B,0,stream>>>(inv,bary,a,N,out);
}

// Round 3
// 2351.979 us; speedup vs baseline: 5.4951x; 5.4951x over previous
//
#include <hip/hip_runtime.h>
#include <stdint.h>

typedef unsigned long long u64;
typedef unsigned int u32;

static constexpr u64 KEMPTY = ~0ull;
static constexpr int PROBE_CAP = 32768;
static constexpr int ACC_TILE = 128;

static __device__ __forceinline__ u64 mix64(u64 x){
  x ^= x >> 30; x *= 0xbf58476d1ce4e5b9ull;
  x ^= x >> 27; x *= 0x94d049bb133111ebull;
  x ^= x >> 31; return x;
}

static __device__ __forceinline__ long long lookup_slot(const u64* __restrict__ tk, u32 cmask, u64 code){
  u32 h = (u32)mix64(code) & cmask;
#pragma unroll 1
  for(int p=0;p<PROBE_CAP;p++){
    u64 cur = tk[h];
    if(cur==code) return (long long)h;
    if(cur==KEMPTY) return -1;
    h=(h+1)&cmask;
  }
  return -1;
}

static __device__ __forceinline__ void atomAddF(float* p, float v){
#if defined(__gfx90a__) || defined(__gfx940__) || defined(__gfx941__) || defined(__gfx942__) || defined(__gfx950__)
  unsafeAtomicAdd(p, v);
#else
  atomicAdd(p, v);
#endif
}

static __device__ __forceinline__ void row_load(const float* __restrict__ p, float* o){
  const float4* q=(const float4*)p;
#pragma unroll
  for(int i=0;i<4;i++){ float4 v=q[i]; o[4*i]=v.x; o[4*i+1]=v.y; o[4*i+2]=v.z; o[4*i+3]=v.w; }
}
static __device__ __forceinline__ void row_store(float* __restrict__ p, const float* o){
  float4* q=(float4*)p;
#pragma unroll
  for(int i=0;i<4;i++) q[i]=make_float4(o[4*i],o[4*i+1],o[4*i+2],o[4*i+3]);
}

__global__ void __launch_bounds__(256)
k_setup(const float* __restrict__ feat, int N,
        u64* __restrict__ tabk, u32 cmask,
        u32* __restrict__ inv_slot, float* __restrict__ bary)
{
#pragma clang fp contract(off)
  int n = blockIdx.x*256 + threadIdx.x;
  if(n>=N) return;

  const float s0=3.4641016151377544f, s1=2.0f, s2=1.4142135623730951f,
              s3=1.0954451150103321f, s4=0.8944271909999159f;
  float c[5];
  c[0]=feat[n*5+0]*s0; c[1]=feat[n*5+1]*s1; c[2]=feat[n*5+2]*s2;
  c[3]=feat[n*5+3]*s3; c[4]=feat[n*5+4]*s4;

  float sfx[6]; sfx[5]=0.f;
#pragma unroll
  for(int i=4;i>=0;i--) sfx[i]=sfx[i+1]+c[i];
  float el[6];
  el[0]=sfx[0];
#pragma unroll
  for(int i=1;i<6;i++) el[i]=sfx[i]-(float)i*c[i-1];

  const float down=1.0f/6.0f;
  float rd[6], rem0[6], rdsum=0.f;
#pragma unroll
  for(int i=0;i<6;i++){ rd[i]=rintf(el[i]*down); rem0[i]=rd[i]*6.0f; rdsum+=rd[i]; }
  int sumi=(int)rdsum;

  float diff[6];
#pragma unroll
  for(int i=0;i<6;i++) diff[i]=(el[i]-rem0[i])*down;

  int rank[6];
#pragma unroll
  for(int i=0;i<6;i++){
    int r=0;
#pragma unroll
    for(int j=0;j<6;j++)
      r += (diff[j]>diff[i]) || (diff[j]==diff[i] && j<i);
    rank[i]=r+sumi;
  }
  int rem0i[6];
#pragma unroll
  for(int i=0;i<6;i++){
    rem0i[i]=(int)rem0[i];
    int sh=(rank[i]<0)-(rank[i]>5);
    rank[i]+=6*sh; rem0i[i]+=6*sh;
  }

  float b[7]={0.f,0.f,0.f,0.f,0.f,0.f,0.f};
#pragma unroll
  for(int i=0;i<6;i++){
    float t=(el[i]-(float)rem0i[i])*down;
    int k0=5-rank[i]; if(k0>=0&&k0<7) b[k0]+=t;
  }
#pragma unroll
  for(int i=0;i<6;i++){
    float t=(el[i]-(float)rem0i[i])*down;
    int k1=6-rank[i]; if(k1>=0&&k1<7) b[k1]-=t;
  }
  bary[(size_t)n*6+0]=(b[0]+1.0f)+b[6];
#pragma unroll
  for(int r=1;r<6;r++) bary[(size_t)n*6+r]=b[r];

#pragma unroll 1
  for(int r=0;r<6;r++){
    long long code=0;
#pragma unroll
    for(int i=0;i<5;i++){
      int key = rem0i[i] + ((rank[i] >= 6-r) ? (r-6) : r);
      code = code*2048 + (long long)(key+1024);
    }
    u32 h=(u32)mix64((u64)code)&cmask;
    u32 slot=0xFFFFFFFFu;
#pragma unroll 1
    for(int p=0;p<PROBE_CAP;p++){
      u64 cur=tabk[h];
      if(cur==(u64)code){ slot=h; break; }
      if(cur==KEMPTY){
        u64 old=atomicCAS((unsigned long long*)&tabk[h], KEMPTY, (u64)code);
        if(old==KEMPTY || old==(u64)code){ slot=h; break; }
      } else {
        h=(h+1)&cmask;
      }
    }
    inv_slot[(size_t)n*6+r]=slot;
  }
}

__global__ void __launch_bounds__(256)
k_uid(const u64* __restrict__ tabk, u32 C, u32 Ucap, u32* __restrict__ tuid,
      u32* __restrict__ uidslot, u32* __restrict__ counter)
{
  u32 s=blockIdx.x*256+threadIdx.x;
  if(s>=C) return;
  if(tabk[s]==KEMPTY) return;
  u32 uid=atomicAdd(counter,1u);
  if(uid<Ucap) uidslot[uid]=s; else uid=0;
  tuid[s]=uid;
}

__global__ void __launch_bounds__(256)
k_inv_count(u32* __restrict__ inv, const u32* __restrict__ tuid,
            u32* __restrict__ cnt, size_t M)
{
  size_t i=(size_t)blockIdx.x*256+threadIdx.x;
  if(i>=M) return;
  u32 u=tuid[inv[i]];
  inv[i]=u;
  atomicAdd(&cnt[u],1u);
}

__global__ void __launch_bounds__(256)
k_scan1(const u32* __restrict__ cnt, u32* __restrict__ bsum)
{
  __shared__ u32 sm[256];
  u32 t=threadIdx.x, b=blockIdx.x;
  size_t base=((size_t)b*256+t)*4;
  u32 s=cnt[base]+cnt[base+1]+cnt[base+2]+cnt[base+3];
  sm[t]=s; __syncthreads();
  for(int o=128;o>0;o>>=1){ if(t<(u32)o) sm[t]+=sm[t+o]; __syncthreads(); }
  if(t==0) bsum[b]=sm[0];
}

__global__ void __launch_bounds__(256)
k_scan2(u32* __restrict__ bsum, u32 nb)
{
  __shared__ u32 sm[256];
  u32 t=threadIdx.x;
  u32 e[4]; u32 tot=0;
#pragma unroll
  for(int j=0;j<4;j++){ u32 idx=t*4+j; e[j]=(idx<nb)?bsum[idx]:0u; tot+=e[j]; }
  sm[t]=tot; __syncthreads();
  for(int o=1;o<256;o<<=1){
    u32 v=sm[t]; u32 add=(t>=(u32)o)?sm[t-o]:0u; __syncthreads();
    sm[t]=v+add; __syncthreads();
  }
  u32 excl=sm[t]-tot;
  u32 run=excl;
#pragma unroll
  for(int j=0;j<4;j++){ u32 idx=t*4+j; if(idx<nb) bsum[idx]=run; run+=e[j]; }
}

__global__ void __launch_bounds__(256)
k_scan3(const u32* __restrict__ cnt, const u32* __restrict__ bsum,
        u32* __restrict__ off, u32* __restrict__ cur)
{
  __shared__ u32 sm[256];
  u32 t=threadIdx.x, b=blockIdx.x;
  size_t base=((size_t)b*256+t)*4;
  u32 c[4]; u32 tot=0;
#pragma unroll
  for(int j=0;j<4;j++){ c[j]=cnt[base+j]; tot+=c[j]; }
  sm[t]=tot; __syncthreads();
  for(int o=1;o<256;o<<=1){
    u32 v=sm[t]; u32 add=(t>=(u32)o)?sm[t-o]:0u; __syncthreads();
    sm[t]=v+add; __syncthreads();
  }
  u32 excl=sm[t]-tot;
  u32 run=bsum[b]+excl;
#pragma unroll
  for(int j=0;j<4;j++){ off[base+j]=run; cur[base+j]=run; run+=c[j]; }
}

__global__ void __launch_bounds__(256)
k_scatter(const u32* __restrict__ inv, u32* __restrict__ cur,
          u32* __restrict__ bdata, u32* __restrict__ buid, size_t M)
{
  size_t i=(size_t)blockIdx.x*256+threadIdx.x;
  if(i>=M) return;
  u32 u=inv[i];
  u32 p=atomicAdd(&cur[u],1u);
  bdata[p]=(u32)i;
  buid[p]=u;
}

__global__ void __launch_bounds__(256)
k_accum(const u32* __restrict__ bdata, const u32* __restrict__ buid,
        const float* __restrict__ bary, const float* __restrict__ values,
        const u32* __restrict__ off, const u32* __restrict__ cnt,
        float* __restrict__ v0, size_t M)
{
  u32 gtid=blockIdx.x*256+threadIdx.x;
  u32 wave=gtid>>6;
  u32 lane=threadIdx.x&63;
  if(lane>=16) return;
  size_t tstart=(size_t)wave*ACC_TILE;
  if(tstart>=M) return;
  size_t tend=tstart+ACC_TILE; if(tend>M) tend=M;
  int k=(int)lane;

  u32 cu=buid[tstart];
  float a=0.f;
#pragma unroll 1
  for(size_t p=tstart;p<tend;p++){
    u32 u=buid[p];
    u32 i=bdata[p];
    if(u!=cu){
      bool interior=(off[cu]>=(u32)tstart)&&(off[cu]+cnt[cu]<=(u32)tend);
      float* dst=v0+(size_t)cu*16+k;
      if(interior) *dst=a; else atomAddF(dst,a);
      a=0.f; cu=u;
    }
    a += bary[i]*values[(size_t)(i/6u)*16+k];
  }
  {
    bool interior=(off[cu]>=(u32)tstart)&&(off[cu]+cnt[cu]<=(u32)tend);
    float* dst=v0+(size_t)cu*16+k;
    if(interior) *dst=a; else atomAddF(dst,a);
  }
}

__global__ void __launch_bounds__(256)
k_blur(const u64* __restrict__ tabk, const u32* __restrict__ tuid, u32 cmask,
       const u32* __restrict__ uidslot, const u32* __restrict__ counter, u32 Ucap,
       long long delta, const float* __restrict__ vin, float* __restrict__ vout)
{
  u32 m=blockIdx.x*256+threadIdx.x;
  u32 U=*counter; if(U>Ucap) U=Ucap;
  if(m>=U) return;
  long long code=(long long)tabk[uidslot[m]];
  long long sp=lookup_slot(tabk,cmask,(u64)(code+delta));
  long long sm=lookup_slot(tabk,cmask,(u64)(code-delta));
  float acc[16];
  row_load(vin+(size_t)m*16, acc);
#pragma unroll
  for(int k=0;k<16;k++) acc[k]*=0.5f;
  if(sp>=0){
    u32 u=tuid[sp]; float t[16]; row_load(vin+(size_t)u*16,t);
#pragma unroll
    for(int k=0;k<16;k++) acc[k]+=0.25f*t[k];
  }
  if(sm>=0){
    u32 u=tuid[sm]; float t[16]; row_load(vin+(size_t)u*16,t);
#pragma unroll
    for(int k=0;k<16;k++) acc[k]+=0.25f*t[k];
  }
  row_store(vout+(size_t)m*16, acc);
}

__global__ void __launch_bounds__(256)
k_slice(const u32* __restrict__ inv, const float* __restrict__ bary,
        const float* __restrict__ val, int N, float* __restrict__ out)
{
  int n=blockIdx.x*256+threadIdx.x;
  if(n>=N) return;
  float acc[16];
#pragma unroll
  for(int k=0;k<16;k++) acc[k]=0.f;
#pragma unroll 1
  for(int r=0;r<6;r++){
    u32 u=inv[(size_t)n*6+r];
    float w=bary[(size_t)n*6+r];
    float t[16]; row_load(val+(size_t)u*16,t);
#pragma unroll
    for(int k=0;k<16;k++) acc[k]+=w*t[k];
  }
  const float alpha=0.9696969696969697f;
  float4* q=(float4*)(out+(size_t)n*16);
#pragma unroll
  for(int i=0;i<4;i++) q[i]=make_float4(alpha*acc[4*i],alpha*acc[4*i+1],alpha*acc[4*i+2],alpha*acc[4*i+3]);
}

__global__ void k_diag(float* out, float v){ out[0]=v; }

extern "C" void kernel_launch(void* const* d_in, const int* in_sizes, int n_in,
                              void* d_out, int out_size, void* d_ws, size_t ws_size,
                              hipStream_t stream)
{
  const float* feat   =(const float*)d_in[0];
  const float* values =(const float*)d_in[1];
  float* out=(float*)d_out;
  int N=in_sizes[0]/5;
  size_t M=(size_t)N*6;

  // v1 region doubles as splat scratch: cnt[U] off[U] cur[U] bdata[M] buid[M] bsum[U/1024]
  auto v1bytes=[&](size_t U)->size_t{
    size_t a=U*64, b=U*12+M*8+(U/1024)*4;
    return a>b?a:b;
  };
  auto need=[&](int lC,int lU)->size_t{
    size_t C=1ull<<lC, U=1ull<<lU, s=0;
    auto al=[&](size_t b){ s=(s+255)&~(size_t)255; s+=b; };
    al(4); al(M*4); al(M*4); al(C*8); al(C*4); al(U*4); al(U*64); al(v1bytes(U));
    return s+256;
  };
  const int prefs[4][2]={{22,20},{21,20},{21,19},{20,18}};
  int lC=0,lU=0;
  for(int i=0;i<4;i++){ if(need(prefs[i][0],prefs[i][1])<=ws_size){ lC=prefs[i][0]; lU=prefs[i][1]; break; } }
  if(!lC){
    hipMemsetAsync(d_out,0,(size_t)out_size*sizeof(float),stream);
    k_diag<<<1,1,0,stream>>>(out,(float)(ws_size>>20));
    return;
  }

  size_t C=1ull<<lC, Ucap=1ull<<lU; u32 cmask=(u32)(C-1);
  char* base=(char*)d_ws; size_t offb=0;
  auto carve=[&](size_t b)->char*{ offb=(offb+255)&~(size_t)255; char* p=base+offb; offb+=b; return p; };
  u32*   counter=(u32*)carve(4);
  u32*   inv    =(u32*)carve(M*4);
  float* bary   =(float*)carve(M*4);
  u64*   tabk   =(u64*)carve(C*8);
  u32*   tuid   =(u32*)carve(C*4);
  u32*   uidslot=(u32*)carve(Ucap*4);
  float* v0     =(float*)carve(Ucap*64);
  float* v1     =(float*)carve(v1bytes(Ucap));

  u32* cnt  =(u32*)v1;
  u32* off  =cnt+Ucap;
  u32* cur  =off+Ucap;
  u32* bdata=cur+Ucap;
  u32* buid =bdata+M;
  u32* bsum =buid+M;

  hipMemsetAsync(counter,0,4,stream);
  hipMemsetAsync(tabk,0xFF,C*8,stream);
  hipMemsetAsync(cnt,0,Ucap*4,stream);
  hipMemsetAsync(v0,0,Ucap*64,stream);

  const int B=256;
  u32 nb=(u32)(Ucap/1024);
  k_setup    <<<(N+B-1)/B,B,0,stream>>>(feat,N,tabk,cmask,inv,bary);
  k_uid      <<<(u32)((C+B-1)/B),B,0,stream>>>(tabk,(u32)C,(u32)Ucap,tuid,uidslot,counter);
  k_inv_count<<<(u32)((M+B-1)/B),B,0,stream>>>(inv,tuid,cnt,M);
  k_scan1    <<<nb,B,0,stream>>>(cnt,bsum);
  k_scan2    <<<1 ,B,0,stream>>>(bsum,nb);
  k_scan3    <<<nb,B,0,stream>>>(cnt,bsum,off,cur);
  k_scatter  <<<(u32)((M+B-1)/B),B,0,stream>>>(inv,cur,bdata,buid,M);

  u32 waves=(u32)((M+ACC_TILE-1)/ACC_TILE);
  k_accum<<<(waves+3)/4,B,0,stream>>>(bdata,buid,bary,values,off,cnt,v0,M);

  const long long P[5]={1ll,2048ll,1ll<<22,1ll<<33,1ll<<44};
  const long long SUM=P[0]+P[1]+P[2]+P[3]+P[4];
  u32 gb=(u32)((Ucap+B-1)/B);
  float* a=v0; float* bb=v1;
  for(int j=0;j<6;j++){
    long long delta=(j<5)? (SUM-6*P[4-j]) : SUM;
    k_blur<<<gb,B,0,stream>>>(tabk,tuid,cmask,uidslot,counter,(u32)Ucap,delta,a,bb);
    float* t=a; a=bb; bb=t;
  }
  k_slice<<<(N+B-1)/B,B,0,stream>>>(inv,bary,a,N,out);
}